// Round 4
// baseline (755.888 us; speedup 1.0000x reference)
//
#include <hip/hip_runtime.h>
#include <hip/hip_fp16.h>

#define NN 100000
#define NE 1200000
#define NBUK ((NN + 127) / 128)   // 782

struct alignas(8) Half4 { __half2 lo, hi; };

// ---------------- bucketed CSR build ----------------
__global__ __launch_bounds__(1024) void k_zerob(int* bcnt) {
    int i = threadIdx.x;
    if (i <= NBUK) bcnt[i] = 0;
}

// LDS-binned bucket histogram of col>>7
__global__ __launch_bounds__(256) void k_bhist(const int* __restrict__ col, int* __restrict__ bcnt) {
    __shared__ int lh[NBUK];
    for (int i = threadIdx.x; i < NBUK; i += 256) lh[i] = 0;
    __syncthreads();
    for (int e = blockIdx.x * 256 + threadIdx.x; e < NE; e += 256 * 256)
        atomicAdd(&lh[col[e] >> 7], 1);
    __syncthreads();
    for (int i = threadIdx.x; i < NBUK; i += 256) {
        int v = lh[i];
        if (v) atomicAdd(&bcnt[i], v);
    }
}

// single-block exclusive scan of bcnt[NBUK] -> bcnt (bases) and bcur
__global__ __launch_bounds__(1024) void k_bscan(int* __restrict__ bcnt, int* __restrict__ bcur) {
    __shared__ int s[1024];
    int tid = threadIdx.x;
    int v = (tid < NBUK) ? bcnt[tid] : 0;
    s[tid] = v;
    __syncthreads();
    #pragma unroll
    for (int d = 1; d < 1024; d <<= 1) {
        int t = (tid >= d) ? s[tid - d] : 0;
        __syncthreads();
        s[tid] += t;
        __syncthreads();
    }
    if (tid < NBUK) {
        int excl = s[tid] - v;
        bcnt[tid] = excl;
        bcur[tid] = excl;
    }
    if (tid == 0) bcnt[NBUK] = NE;
}

// pass A: append packed (row<<7 | col&127) into bucket segment
__global__ __launch_bounds__(256) void k_bucket(const int* __restrict__ row,
                                                const int* __restrict__ col,
                                                int* __restrict__ bcur,
                                                unsigned* __restrict__ tmp) {
    int e = blockIdx.x * 256 + threadIdx.x;
    if (e >= NE) return;
    int c = col[e], r = row[e];
    int pos = atomicAdd(&bcur[c >> 7], 1);
    tmp[pos] = ((unsigned)r << 7) | (unsigned)(c & 127);
}

// pass B: per-bucket LDS hist + scan -> off/dinv, then LDS-cursor scatter into csr_row
__global__ __launch_bounds__(256) void k_build(const unsigned* __restrict__ tmp,
                                               const int* __restrict__ bbase,
                                               int* __restrict__ off,
                                               float* __restrict__ dinv,
                                               int* __restrict__ csr_row) {
    __shared__ int cnt[128], s[128], cur[128];
    const int b = blockIdx.x, tid = threadIdx.x;
    const int colBase = b << 7;
    const int nCols = (NN - colBase < 128) ? (NN - colBase) : 128;
    const int seg0 = bbase[b], seg1 = bbase[b + 1];
    if (tid < 128) cnt[tid] = 0;
    __syncthreads();
    for (int i = seg0 + tid; i < seg1; i += 256)
        atomicAdd(&cnt[tmp[i] & 127], 1);
    __syncthreads();
    if (tid < 128) s[tid] = cnt[tid];
    __syncthreads();
    #pragma unroll
    for (int d = 1; d < 128; d <<= 1) {
        int t = (tid < 128 && tid >= d) ? s[tid - d] : 0;
        __syncthreads();
        if (tid < 128) s[tid] += t;
        __syncthreads();
    }
    if (tid < nCols) {
        int exc = seg0 + s[tid] - cnt[tid];
        off[colBase + tid] = exc;
        cur[tid] = exc;
        dinv[colBase + tid] = rsqrtf((float)cnt[tid] + 1.0f);
    }
    if (b == 0 && tid == 0) off[NN] = NE;
    __syncthreads();
    for (int i = seg0 + tid; i < seg1; i += 256) {
        unsigned v = tmp[i];
        int pos = atomicAdd(&cur[v & 127u], 1);
        csr_row[pos] = (int)(v >> 7);
    }
}

// ---------------- GEMM ----------------
// OUTH: write fp16, scaled by dinv[n].  BYP: also compute byp[n][0..2] = x@bypW.T + bypb.
template<int D, int BN, bool OUTH, bool BYP>
__global__ __launch_bounds__(256) void k_gemm(const float* __restrict__ X,
                                              const float* __restrict__ W,
                                              const float* __restrict__ bias,
                                              const float* __restrict__ dinv,
                                              float* __restrict__ Y,
                                              __half* __restrict__ Yh,
                                              const float* __restrict__ bypW,
                                              const float* __restrict__ bypb,
                                              float* __restrict__ bypOut,
                                              int n_nodes) {
    __shared__ float Wt[D * 64];         // Wt[d*64+j]
    __shared__ float Xl[BN * (D + 1)];   // padded rows
    __shared__ float BWs[BYP ? 387 : 1];
    const int tid = threadIdx.x;
    const int n0 = blockIdx.x * BN;

    for (int idx = tid; idx < 64 * D; idx += 256) {
        int j = idx / D, d = idx - j * D;
        Wt[d * 64 + j] = W[idx];
    }
    for (int idx = tid; idx < BN * D; idx += 256) {
        int nl = idx / D, d = idx - nl * D;
        int n = n0 + nl; if (n >= n_nodes) n = n_nodes - 1;
        Xl[nl * (D + 1) + d] = X[(size_t)n * D + d];
    }
    if constexpr (BYP) {
        for (int idx = tid; idx < 387; idx += 256)
            BWs[idx] = (idx < 384) ? bypW[idx] : bypb[idx - 384];
    }
    __syncthreads();

    const int j0 = (tid & 15) * 4;
    const int nl = tid >> 4;             // 0..15
    constexpr int K = BN / 16;
    float acc[K][4];
    float b0 = 0.f, b1 = 0.f, b2 = 0.f, b3 = 0.f;
    if (bias) { b0 = bias[j0]; b1 = bias[j0 + 1]; b2 = bias[j0 + 2]; b3 = bias[j0 + 3]; }
    #pragma unroll
    for (int k = 0; k < K; k++) { acc[k][0] = b0; acc[k][1] = b1; acc[k][2] = b2; acc[k][3] = b3; }

    #pragma unroll 4
    for (int d = 0; d < D; d++) {
        const float4 w4 = *(const float4*)&Wt[d * 64 + j0];
        #pragma unroll
        for (int k = 0; k < K; k++) {
            float xv = Xl[(nl + 16 * k) * (D + 1) + d];
            acc[k][0] += xv * w4.x; acc[k][1] += xv * w4.y;
            acc[k][2] += xv * w4.z; acc[k][3] += xv * w4.w;
        }
    }
    #pragma unroll
    for (int k = 0; k < K; k++) {
        int n = n0 + nl + 16 * k;
        if (n < n_nodes) {
            if constexpr (OUTH) {
                float s = dinv[n];
                Half4 h;
                h.lo = __floats2half2_rn(acc[k][0] * s, acc[k][1] * s);
                h.hi = __floats2half2_rn(acc[k][2] * s, acc[k][3] * s);
                *(Half4*)&Yh[(size_t)n * 64 + j0] = h;
            } else {
                *(float4*)&Y[(size_t)n * 64 + j0] =
                    make_float4(acc[k][0], acc[k][1], acc[k][2], acc[k][3]);
            }
        }
    }
    if constexpr (BYP) {
        if (tid < 96) {
            int nl2 = tid & 31, o = tid >> 5;
            float b = BWs[384 + o];
            #pragma unroll 8
            for (int d = 0; d < D; d++)
                b += Xl[nl2 * (D + 1) + d] * BWs[o * 128 + d];
            int n = n0 + nl2;
            if (n < n_nodes) bypOut[n * 3 + o] = b;
        }
    }
}

// ---------------- fused pull-aggregation ----------------
template<bool RES, bool HEAD>
__global__ __launch_bounds__(256) void k_gather(const __half* __restrict__ hBh,
                                                const float* __restrict__ dinv,
                                                const int* __restrict__ off,
                                                const int* __restrict__ csr_row,
                                                const float* __restrict__ convb,
                                                const float* __restrict__ bng,
                                                const float* __restrict__ bnb,
                                                float* __restrict__ hA,
                                                const float* __restrict__ byp,
                                                const float* __restrict__ headW,
                                                const float* __restrict__ headb,
                                                float* __restrict__ out) {
    __shared__ float HWs[HEAD ? 204 : 1];
    const int tid = threadIdx.x;
    if constexpr (HEAD) {
        for (int i = tid; i < 204; i += 256)
            HWs[i] = (i < 201) ? headW[i] : headb[i - 201];
        __syncthreads();
    }
    const int n = blockIdx.x * 4 + (tid >> 6);   // grid = NN/4 exactly
    const int lane = tid & 63;
    const int g = lane >> 3, s = lane & 7;
    const int f0 = s * 8;

    const int e0 = off[n], eEnd = off[n + 1];
    float acc[8] = {0, 0, 0, 0, 0, 0, 0, 0};
    const int nIter = (eEnd - e0 + 7) >> 3;
    for (int t = 0; t < nIter; ++t) {
        int idx = e0 + t * 8 + g;
        float w = (idx < eEnd) ? 1.0f : 0.0f;
        int idxc = (idx < eEnd) ? idx : (eEnd - 1);
        int r = csr_row[idxc];
        float4 raw = *(const float4*)(hBh + ((size_t)r << 6) + f0);
        const __half2* h2 = (const __half2*)&raw;
        #pragma unroll
        for (int q = 0; q < 4; ++q) {
            float2 f = __half22float2(h2[q]);
            acc[2 * q]     = fmaf(w, f.x, acc[2 * q]);
            acc[2 * q + 1] = fmaf(w, f.y, acc[2 * q + 1]);
        }
    }
    #pragma unroll
    for (int m = 8; m < 64; m <<= 1) {
        #pragma unroll
        for (int j = 0; j < 8; ++j)
            acc[j] += __shfl_xor(acc[j], m, 64);
    }
    {   // self-loop term
        float4 raw = *(const float4*)(hBh + ((size_t)n << 6) + f0);
        const __half2* h2 = (const __half2*)&raw;
        #pragma unroll
        for (int q = 0; q < 4; ++q) {
            float2 f = __half22float2(h2[q]);
            acc[2 * q]     += f.x;
            acc[2 * q + 1] += f.y;
        }
    }
    const float dv = dinv[n];
    const float bnscale = rsqrtf(1.0f + 1e-5f);
    float v[8];
    #pragma unroll
    for (int j = 0; j < 8; ++j) {
        float sc = bng[f0 + j] * bnscale;
        v[j] = fmaxf((acc[j] * dv + convb[f0 + j]) * sc + bnb[f0 + j], 0.0f);
    }
    if constexpr (!HEAD) {
        if (g == 0) {
            size_t o = ((size_t)n << 6) + f0;
            if constexpr (RES) {
                #pragma unroll
                for (int j = 0; j < 8; ++j) v[j] += hA[o + j];
            }
            *(float4*)&hA[o]     = make_float4(v[0], v[1], v[2], v[3]);
            *(float4*)&hA[o + 4] = make_float4(v[4], v[5], v[6], v[7]);
        }
    } else {
        float p[3];
        #pragma unroll
        for (int o = 0; o < 3; ++o) {
            float t = 0.f;
            #pragma unroll
            for (int j = 0; j < 8; ++j) t += v[j] * HWs[o * 67 + f0 + j];
            p[o] = t;
        }
        #pragma unroll
        for (int m = 1; m < 8; m <<= 1) {
            #pragma unroll
            for (int o = 0; o < 3; ++o) p[o] += __shfl_xor(p[o], m, 64);
        }
        float b0 = byp[n * 3], b1 = byp[n * 3 + 1], b2 = byp[n * 3 + 2];
        #pragma unroll
        for (int o = 0; o < 3; ++o)
            p[o] += b0 * HWs[o * 67 + 64] + b1 * HWs[o * 67 + 65] + b2 * HWs[o * 67 + 66]
                  + HWs[201 + o];
        if (lane == 0) {
            float kappa = fminf(fmaxf(p[0] * 5.0f + 2.5f, 0.2f), 10.0f);
            float tau   = fminf(fmaxf(p[2] + 0.5f, 0.05f), 2.0f);
            out[(size_t)n * 3]     = kappa;
            out[(size_t)n * 3 + 1] = p[1];
            out[(size_t)n * 3 + 2] = tau;
        }
    }
}

extern "C" void kernel_launch(void* const* d_in, const int* in_sizes, int n_in,
                              void* d_out, int out_size, void* d_ws, size_t ws_size,
                              hipStream_t stream) {
    const float* x     = (const float*)d_in[0];
    const int*   ei    = (const int*)d_in[1];
    const int*   row   = ei;
    const int*   col   = ei + NE;
    const float* projW = (const float*)d_in[2];
    const float* projb = (const float*)d_in[3];
    const float* convW[3] = { (const float*)d_in[4], (const float*)d_in[8],  (const float*)d_in[12] };
    const float* convb[3] = { (const float*)d_in[5], (const float*)d_in[9],  (const float*)d_in[13] };
    const float* bng[3]   = { (const float*)d_in[6], (const float*)d_in[10], (const float*)d_in[14] };
    const float* bnb[3]   = { (const float*)d_in[7], (const float*)d_in[11], (const float*)d_in[15] };
    const float* bypW  = (const float*)d_in[16];
    const float* bypb  = (const float*)d_in[17];
    const float* headW = (const float*)d_in[18];
    const float* headb = (const float*)d_in[19];
    float* out = (float*)d_out;

    float*  ws   = (float*)d_ws;
    float*  dinv = ws;                                  // 102400 floats
    float*  hA   = ws + 102400;                         // NN*64 fp32
    __half* hBh  = (__half*)(hA + (size_t)NN * 64);     // NN*64 fp16
    float*  byp  = (float*)(hBh + (size_t)NN * 64);     // NN*3 (+pad)
    int*    off     = (int*)(byp + 300032);             // NN+1 (pad 100096)
    int*    csr_row = off + 100096;                     // NE
    int*    bcnt    = csr_row + NE;                     // NBUK+1 (pad 784)
    int*    bcur    = bcnt + 784;                       // NBUK
    unsigned* tmp   = (unsigned*)hA;                    // aliases hA (consumed before proj)

    // bucketed CSR build (+dinv +off)
    k_zerob<<<1, 1024, 0, stream>>>(bcnt);
    k_bhist<<<256, 256, 0, stream>>>(col, bcnt);
    k_bscan<<<1, 1024, 0, stream>>>(bcnt, bcur);
    k_bucket<<<(NE + 255) / 256, 256, 0, stream>>>(row, col, bcur, tmp);
    k_build<<<NBUK, 256, 0, stream>>>(tmp, bcnt, off, dinv, csr_row);

    // proj: hA = x @ projW.T + projb  (fp32 out) + byp = x @ bypW.T + bypb
    k_gemm<128, 32, false, true><<<NN / 32, 256, 0, stream>>>(
        x, projW, projb, nullptr, hA, nullptr, bypW, bypb, byp, NN);

    for (int l = 0; l < 3; l++) {
        // hBh = (hA @ convW.T) * dinv   (fp16 out, bias deferred)
        k_gemm<64, 64, true, false><<<(NN + 63) / 64, 256, 0, stream>>>(
            hA, convW[l], nullptr, dinv, nullptr, hBh, nullptr, nullptr, nullptr, NN);
        if (l < 2)
            k_gather<true, false><<<NN / 4, 256, 0, stream>>>(
                hBh, dinv, off, csr_row, convb[l], bng[l], bnb[l], hA,
                nullptr, nullptr, nullptr, nullptr);
        else
            k_gather<false, true><<<NN / 4, 256, 0, stream>>>(
                hBh, dinv, off, csr_row, convb[l], bng[l], bnb[l], nullptr,
                byp, headW, headb, out);
    }
}

// Round 5
// 486.589 us; speedup vs baseline: 1.5534x; 1.5534x over previous
//
#include <hip/hip_runtime.h>
#include <hip/hip_fp16.h>

#define NN 100000
#define NE 1200000
#define NBUK ((NN + 127) / 128)   // 782
#define NCHUNK 256                // blocks in pass A

struct alignas(8) Half4 { __half2 lo, hi; };

// ---------------- bucketed CSR build ----------------
__global__ __launch_bounds__(1024) void k_zerob(int* bcnt) {
    int i = threadIdx.x;
    if (i <= NBUK) bcnt[i] = 0;
}

// LDS-binned bucket histogram of col>>7
__global__ __launch_bounds__(256) void k_bhist(const int* __restrict__ col, int* __restrict__ bcnt) {
    __shared__ int lh[NBUK];
    for (int i = threadIdx.x; i < NBUK; i += 256) lh[i] = 0;
    __syncthreads();
    for (int e = blockIdx.x * 256 + threadIdx.x; e < NE; e += 256 * 256)
        atomicAdd(&lh[col[e] >> 7], 1);
    __syncthreads();
    for (int i = threadIdx.x; i < NBUK; i += 256) {
        int v = lh[i];
        if (v) atomicAdd(&bcnt[i], v);
    }
}

// single-block exclusive scan of bcnt[NBUK] -> bcnt (segment bases) and bcur (rolling cursors)
__global__ __launch_bounds__(1024) void k_bscan(int* __restrict__ bcnt, int* __restrict__ bcur) {
    __shared__ int s[1024];
    int tid = threadIdx.x;
    int v = (tid < NBUK) ? bcnt[tid] : 0;
    s[tid] = v;
    __syncthreads();
    #pragma unroll
    for (int d = 1; d < 1024; d <<= 1) {
        int t = (tid >= d) ? s[tid - d] : 0;
        __syncthreads();
        s[tid] += t;
        __syncthreads();
    }
    if (tid < NBUK) {
        int excl = s[tid] - v;
        bcnt[tid] = excl;
        bcur[tid] = excl;
    }
    if (tid == 0) bcnt[NBUK] = NE;
}

// pass A: per-block LDS hist -> one global reservation per (block,bucket) -> LDS-cursor scatter.
// Each block owns a contiguous edge chunk; its writes per bucket fill a contiguous reserved run.
__global__ __launch_bounds__(256) void k_bucket(const int* __restrict__ row,
                                                const int* __restrict__ col,
                                                int* __restrict__ bcur,
                                                unsigned* __restrict__ tmp) {
    __shared__ int lh[NBUK];
    const int tid = threadIdx.x;
    const int per = (NE + NCHUNK - 1) / NCHUNK;           // 4688
    const int e0 = blockIdx.x * per;
    const int e1 = (e0 + per < NE) ? (e0 + per) : NE;
    for (int i = tid; i < NBUK; i += 256) lh[i] = 0;
    __syncthreads();
    for (int e = e0 + tid; e < e1; e += 256)
        atomicAdd(&lh[col[e] >> 7], 1);
    __syncthreads();
    for (int b = tid; b < NBUK; b += 256) {
        int c = lh[b];
        if (c) lh[b] = atomicAdd(&bcur[b], c);
    }
    __syncthreads();
    for (int e = e0 + tid; e < e1; e += 256) {
        int c = col[e], r = row[e];
        int pos = atomicAdd(&lh[c >> 7], 1);
        tmp[pos] = ((unsigned)r << 7) | (unsigned)(c & 127);
    }
}

// pass B: per-bucket LDS hist + scan -> off/dinv, then LDS-cursor scatter into csr_row
__global__ __launch_bounds__(256) void k_build(const unsigned* __restrict__ tmp,
                                               const int* __restrict__ bbase,
                                               int* __restrict__ off,
                                               float* __restrict__ dinv,
                                               int* __restrict__ csr_row) {
    __shared__ int cnt[128], s[128], cur[128];
    const int b = blockIdx.x, tid = threadIdx.x;
    const int colBase = b << 7;
    const int nCols = (NN - colBase < 128) ? (NN - colBase) : 128;
    const int seg0 = bbase[b], seg1 = bbase[b + 1];
    if (tid < 128) cnt[tid] = 0;
    __syncthreads();
    for (int i = seg0 + tid; i < seg1; i += 256)
        atomicAdd(&cnt[tmp[i] & 127], 1);
    __syncthreads();
    if (tid < 128) s[tid] = cnt[tid];
    __syncthreads();
    #pragma unroll
    for (int d = 1; d < 128; d <<= 1) {
        int t = (tid < 128 && tid >= d) ? s[tid - d] : 0;
        __syncthreads();
        if (tid < 128) s[tid] += t;
        __syncthreads();
    }
    if (tid < nCols) {
        int exc = seg0 + s[tid] - cnt[tid];
        off[colBase + tid] = exc;
        cur[tid] = exc;
        dinv[colBase + tid] = rsqrtf((float)cnt[tid] + 1.0f);
    }
    if (b == 0 && tid == 0) off[NN] = NE;
    __syncthreads();
    for (int i = seg0 + tid; i < seg1; i += 256) {
        unsigned v = tmp[i];
        int pos = atomicAdd(&cur[v & 127u], 1);
        csr_row[pos] = (int)(v >> 7);
    }
}

// ---------------- GEMM ----------------
// OUTH: write fp16, scaled by dinv[n].  BYP: also compute byp[n][0..2] = x@bypW.T + bypb.
template<int D, int BN, bool OUTH, bool BYP>
__global__ __launch_bounds__(256) void k_gemm(const float* __restrict__ X,
                                              const float* __restrict__ W,
                                              const float* __restrict__ bias,
                                              const float* __restrict__ dinv,
                                              float* __restrict__ Y,
                                              __half* __restrict__ Yh,
                                              const float* __restrict__ bypW,
                                              const float* __restrict__ bypb,
                                              float* __restrict__ bypOut,
                                              int n_nodes) {
    __shared__ float Wt[D * 64];         // Wt[d*64+j]
    __shared__ float Xl[BN * (D + 1)];   // padded rows
    __shared__ float BWs[BYP ? 387 : 1];
    const int tid = threadIdx.x;
    const int n0 = blockIdx.x * BN;

    for (int idx = tid; idx < 64 * D; idx += 256) {
        int j = idx / D, d = idx - j * D;
        Wt[d * 64 + j] = W[idx];
    }
    for (int idx = tid; idx < BN * D; idx += 256) {
        int nl = idx / D, d = idx - nl * D;
        int n = n0 + nl; if (n >= n_nodes) n = n_nodes - 1;
        Xl[nl * (D + 1) + d] = X[(size_t)n * D + d];
    }
    if constexpr (BYP) {
        for (int idx = tid; idx < 387; idx += 256)
            BWs[idx] = (idx < 384) ? bypW[idx] : bypb[idx - 384];
    }
    __syncthreads();

    const int j0 = (tid & 15) * 4;
    const int nl = tid >> 4;             // 0..15
    constexpr int K = BN / 16;
    float acc[K][4];
    float b0 = 0.f, b1 = 0.f, b2 = 0.f, b3 = 0.f;
    if (bias) { b0 = bias[j0]; b1 = bias[j0 + 1]; b2 = bias[j0 + 2]; b3 = bias[j0 + 3]; }
    #pragma unroll
    for (int k = 0; k < K; k++) { acc[k][0] = b0; acc[k][1] = b1; acc[k][2] = b2; acc[k][3] = b3; }

    #pragma unroll 4
    for (int d = 0; d < D; d++) {
        const float4 w4 = *(const float4*)&Wt[d * 64 + j0];
        #pragma unroll
        for (int k = 0; k < K; k++) {
            float xv = Xl[(nl + 16 * k) * (D + 1) + d];
            acc[k][0] += xv * w4.x; acc[k][1] += xv * w4.y;
            acc[k][2] += xv * w4.z; acc[k][3] += xv * w4.w;
        }
    }
    #pragma unroll
    for (int k = 0; k < K; k++) {
        int n = n0 + nl + 16 * k;
        if (n < n_nodes) {
            if constexpr (OUTH) {
                float s = dinv[n];
                Half4 h;
                h.lo = __floats2half2_rn(acc[k][0] * s, acc[k][1] * s);
                h.hi = __floats2half2_rn(acc[k][2] * s, acc[k][3] * s);
                *(Half4*)&Yh[(size_t)n * 64 + j0] = h;
            } else {
                *(float4*)&Y[(size_t)n * 64 + j0] =
                    make_float4(acc[k][0], acc[k][1], acc[k][2], acc[k][3]);
            }
        }
    }
    if constexpr (BYP) {
        if (tid < 96) {
            int nl2 = tid & 31, o = tid >> 5;
            float b = BWs[384 + o];
            #pragma unroll 8
            for (int d = 0; d < D; d++)
                b += Xl[nl2 * (D + 1) + d] * BWs[o * 128 + d];
            int n = n0 + nl2;
            if (n < n_nodes) bypOut[n * 3 + o] = b;
        }
    }
}

// ---------------- fused pull-aggregation ----------------
template<bool RES, bool HEAD>
__global__ __launch_bounds__(256) void k_gather(const __half* __restrict__ hBh,
                                                const float* __restrict__ dinv,
                                                const int* __restrict__ off,
                                                const int* __restrict__ csr_row,
                                                const float* __restrict__ convb,
                                                const float* __restrict__ bng,
                                                const float* __restrict__ bnb,
                                                float* __restrict__ hA,
                                                const float* __restrict__ byp,
                                                const float* __restrict__ headW,
                                                const float* __restrict__ headb,
                                                float* __restrict__ out) {
    __shared__ float HWs[HEAD ? 204 : 1];
    const int tid = threadIdx.x;
    if constexpr (HEAD) {
        for (int i = tid; i < 204; i += 256)
            HWs[i] = (i < 201) ? headW[i] : headb[i - 201];
        __syncthreads();
    }
    const int n = blockIdx.x * 4 + (tid >> 6);   // grid = NN/4 exactly
    const int lane = tid & 63;
    const int g = lane >> 3, s = lane & 7;
    const int f0 = s * 8;

    const int e0 = off[n], eEnd = off[n + 1];
    float acc[8] = {0, 0, 0, 0, 0, 0, 0, 0};
    const int nIter = (eEnd - e0 + 7) >> 3;
    for (int t = 0; t < nIter; ++t) {
        int idx = e0 + t * 8 + g;
        float w = (idx < eEnd) ? 1.0f : 0.0f;
        int idxc = (idx < eEnd) ? idx : (eEnd - 1);
        int r = csr_row[idxc];
        float4 raw = *(const float4*)(hBh + ((size_t)r << 6) + f0);
        const __half2* h2 = (const __half2*)&raw;
        #pragma unroll
        for (int q = 0; q < 4; ++q) {
            float2 f = __half22float2(h2[q]);
            acc[2 * q]     = fmaf(w, f.x, acc[2 * q]);
            acc[2 * q + 1] = fmaf(w, f.y, acc[2 * q + 1]);
        }
    }
    #pragma unroll
    for (int m = 8; m < 64; m <<= 1) {
        #pragma unroll
        for (int j = 0; j < 8; ++j)
            acc[j] += __shfl_xor(acc[j], m, 64);
    }
    {   // self-loop term
        float4 raw = *(const float4*)(hBh + ((size_t)n << 6) + f0);
        const __half2* h2 = (const __half2*)&raw;
        #pragma unroll
        for (int q = 0; q < 4; ++q) {
            float2 f = __half22float2(h2[q]);
            acc[2 * q]     += f.x;
            acc[2 * q + 1] += f.y;
        }
    }
    const float dv = dinv[n];
    const float bnscale = rsqrtf(1.0f + 1e-5f);
    float v[8];
    #pragma unroll
    for (int j = 0; j < 8; ++j) {
        float sc = bng[f0 + j] * bnscale;
        v[j] = fmaxf((acc[j] * dv + convb[f0 + j]) * sc + bnb[f0 + j], 0.0f);
    }
    if constexpr (!HEAD) {
        if (g == 0) {
            size_t o = ((size_t)n << 6) + f0;
            if constexpr (RES) {
                #pragma unroll
                for (int j = 0; j < 8; ++j) v[j] += hA[o + j];
            }
            *(float4*)&hA[o]     = make_float4(v[0], v[1], v[2], v[3]);
            *(float4*)&hA[o + 4] = make_float4(v[4], v[5], v[6], v[7]);
        }
    } else {
        float p[3];
        #pragma unroll
        for (int o = 0; o < 3; ++o) {
            float t = 0.f;
            #pragma unroll
            for (int j = 0; j < 8; ++j) t += v[j] * HWs[o * 67 + f0 + j];
            p[o] = t;
        }
        #pragma unroll
        for (int m = 1; m < 8; m <<= 1) {
            #pragma unroll
            for (int o = 0; o < 3; ++o) p[o] += __shfl_xor(p[o], m, 64);
        }
        float b0 = byp[n * 3], b1 = byp[n * 3 + 1], b2 = byp[n * 3 + 2];
        #pragma unroll
        for (int o = 0; o < 3; ++o)
            p[o] += b0 * HWs[o * 67 + 64] + b1 * HWs[o * 67 + 65] + b2 * HWs[o * 67 + 66]
                  + HWs[201 + o];
        if (lane == 0) {
            float kappa = fminf(fmaxf(p[0] * 5.0f + 2.5f, 0.2f), 10.0f);
            float tau   = fminf(fmaxf(p[2] + 0.5f, 0.05f), 2.0f);
            out[(size_t)n * 3]     = kappa;
            out[(size_t)n * 3 + 1] = p[1];
            out[(size_t)n * 3 + 2] = tau;
        }
    }
}

extern "C" void kernel_launch(void* const* d_in, const int* in_sizes, int n_in,
                              void* d_out, int out_size, void* d_ws, size_t ws_size,
                              hipStream_t stream) {
    const float* x     = (const float*)d_in[0];
    const int*   ei    = (const int*)d_in[1];
    const int*   row   = ei;
    const int*   col   = ei + NE;
    const float* projW = (const float*)d_in[2];
    const float* projb = (const float*)d_in[3];
    const float* convW[3] = { (const float*)d_in[4], (const float*)d_in[8],  (const float*)d_in[12] };
    const float* convb[3] = { (const float*)d_in[5], (const float*)d_in[9],  (const float*)d_in[13] };
    const float* bng[3]   = { (const float*)d_in[6], (const float*)d_in[10], (const float*)d_in[14] };
    const float* bnb[3]   = { (const float*)d_in[7], (const float*)d_in[11], (const float*)d_in[15] };
    const float* bypW  = (const float*)d_in[16];
    const float* bypb  = (const float*)d_in[17];
    const float* headW = (const float*)d_in[18];
    const float* headb = (const float*)d_in[19];
    float* out = (float*)d_out;

    float*  ws   = (float*)d_ws;
    float*  dinv = ws;                                  // 102400 floats
    float*  hA   = ws + 102400;                         // NN*64 fp32
    __half* hBh  = (__half*)(hA + (size_t)NN * 64);     // NN*64 fp16
    float*  byp  = (float*)(hBh + (size_t)NN * 64);     // NN*3 (+pad)
    int*    off     = (int*)(byp + 300032);             // NN+1 (pad 100096)
    int*    csr_row = off + 100096;                     // NE
    int*    bcnt    = csr_row + NE;                     // NBUK+1 (pad 784)
    int*    bcur    = bcnt + 784;                       // NBUK
    unsigned* tmp   = (unsigned*)hA;                    // aliases hA (consumed before proj)

    // bucketed CSR build (+dinv +off)
    k_zerob<<<1, 1024, 0, stream>>>(bcnt);
    k_bhist<<<256, 256, 0, stream>>>(col, bcnt);
    k_bscan<<<1, 1024, 0, stream>>>(bcnt, bcur);
    k_bucket<<<NCHUNK, 256, 0, stream>>>(row, col, bcur, tmp);
    k_build<<<NBUK, 256, 0, stream>>>(tmp, bcnt, off, dinv, csr_row);

    // proj: hA = x @ projW.T + projb  (fp32 out) + byp = x @ bypW.T + bypb
    k_gemm<128, 32, false, true><<<NN / 32, 256, 0, stream>>>(
        x, projW, projb, nullptr, hA, nullptr, bypW, bypb, byp, NN);

    for (int l = 0; l < 3; l++) {
        // hBh = (hA @ convW.T) * dinv   (fp16 out, bias deferred)
        k_gemm<64, 64, true, false><<<(NN + 63) / 64, 256, 0, stream>>>(
            hA, convW[l], nullptr, dinv, nullptr, hBh, nullptr, nullptr, nullptr, NN);
        if (l < 2)
            k_gather<true, false><<<NN / 4, 256, 0, stream>>>(
                hBh, dinv, off, csr_row, convb[l], bng[l], bnb[l], hA,
                nullptr, nullptr, nullptr, nullptr);
        else
            k_gather<false, true><<<NN / 4, 256, 0, stream>>>(
                hBh, dinv, off, csr_row, convb[l], bng[l], bnb[l], nullptr,
                byp, headW, headb, out);
    }
}

// Round 6
// 450.852 us; speedup vs baseline: 1.6766x; 1.0793x over previous
//
#include <hip/hip_runtime.h>
#include <hip/hip_fp16.h>

#define NN 100000
#define NE 1200000
#define NBUK ((NN + 127) / 128)   // 782
#define NCHUNK 128                // blocks in pass A

struct alignas(8) Half4 { __half2 lo, hi; };

// ---------------- bucketed CSR build ----------------
__global__ __launch_bounds__(1024) void k_zerob(int* bcnt) {
    int i = threadIdx.x;
    if (i <= NBUK) bcnt[i] = 0;
}

// LDS-binned bucket histogram of col>>7
__global__ __launch_bounds__(256) void k_bhist(const int* __restrict__ col, int* __restrict__ bcnt) {
    __shared__ int lh[NBUK];
    for (int i = threadIdx.x; i < NBUK; i += 256) lh[i] = 0;
    __syncthreads();
    for (int e = blockIdx.x * 256 + threadIdx.x; e < NE; e += 256 * 256)
        atomicAdd(&lh[col[e] >> 7], 1);
    __syncthreads();
    for (int i = threadIdx.x; i < NBUK; i += 256) {
        int v = lh[i];
        if (v) atomicAdd(&bcnt[i], v);
    }
}

// single-block exclusive scan of bcnt[NBUK] -> bcnt (segment bases) and bcur (rolling cursors)
__global__ __launch_bounds__(1024) void k_bscan(int* __restrict__ bcnt, int* __restrict__ bcur) {
    __shared__ int s[1024];
    int tid = threadIdx.x;
    int v = (tid < NBUK) ? bcnt[tid] : 0;
    s[tid] = v;
    __syncthreads();
    #pragma unroll
    for (int d = 1; d < 1024; d <<= 1) {
        int t = (tid >= d) ? s[tid - d] : 0;
        __syncthreads();
        s[tid] += t;
        __syncthreads();
    }
    if (tid < NBUK) {
        int excl = s[tid] - v;
        bcnt[tid] = excl;
        bcur[tid] = excl;
    }
    if (tid == 0) bcnt[NBUK] = NE;
}

// pass A: per-block LDS hist -> one global reservation per (block,bucket) -> LDS-cursor scatter.
__global__ __launch_bounds__(256) void k_bucket(const int* __restrict__ row,
                                                const int* __restrict__ col,
                                                int* __restrict__ bcur,
                                                unsigned* __restrict__ tmp) {
    __shared__ int lh[NBUK];
    const int tid = threadIdx.x;
    const int per = (NE + NCHUNK - 1) / NCHUNK;
    const int e0 = blockIdx.x * per;
    const int e1 = (e0 + per < NE) ? (e0 + per) : NE;
    for (int i = tid; i < NBUK; i += 256) lh[i] = 0;
    __syncthreads();
    for (int e = e0 + tid; e < e1; e += 256)
        atomicAdd(&lh[col[e] >> 7], 1);
    __syncthreads();
    for (int b = tid; b < NBUK; b += 256) {
        int c = lh[b];
        if (c) lh[b] = atomicAdd(&bcur[b], c);
    }
    __syncthreads();
    for (int e = e0 + tid; e < e1; e += 256) {
        int c = col[e], r = row[e];
        int pos = atomicAdd(&lh[c >> 7], 1);
        tmp[pos] = ((unsigned)r << 7) | (unsigned)(c & 127);
    }
}

// pass B: per-bucket LDS hist + scan -> off/dinv, then LDS-cursor scatter into csr_row
__global__ __launch_bounds__(256) void k_build(const unsigned* __restrict__ tmp,
                                               const int* __restrict__ bbase,
                                               int* __restrict__ off,
                                               float* __restrict__ dinv,
                                               int* __restrict__ csr_row) {
    __shared__ int cnt[128], s[128], cur[128];
    const int b = blockIdx.x, tid = threadIdx.x;
    const int colBase = b << 7;
    const int nCols = (NN - colBase < 128) ? (NN - colBase) : 128;
    const int seg0 = bbase[b], seg1 = bbase[b + 1];
    if (tid < 128) cnt[tid] = 0;
    __syncthreads();
    for (int i = seg0 + tid; i < seg1; i += 256)
        atomicAdd(&cnt[tmp[i] & 127], 1);
    __syncthreads();
    if (tid < 128) s[tid] = cnt[tid];
    __syncthreads();
    #pragma unroll
    for (int d = 1; d < 128; d <<= 1) {
        int t = (tid < 128 && tid >= d) ? s[tid - d] : 0;
        __syncthreads();
        if (tid < 128) s[tid] += t;
        __syncthreads();
    }
    if (tid < nCols) {
        int exc = seg0 + s[tid] - cnt[tid];
        off[colBase + tid] = exc;
        cur[tid] = exc;
        dinv[colBase + tid] = rsqrtf((float)cnt[tid] + 1.0f);
    }
    if (b == 0 && tid == 0) off[NN] = NE;
    __syncthreads();
    for (int i = seg0 + tid; i < seg1; i += 256) {
        unsigned v = tmp[i];
        int pos = atomicAdd(&cur[v & 127u], 1);
        csr_row[pos] = (int)(v >> 7);
    }
}

// ---------------- GEMM ----------------
// Wt layout [d][j] (stride 64), staged conflict-free; Xl unpadded [nl][d], flat float4 copy.
// OUTH: write fp16, scaled by dinv[n].  BYP: also byp[n][0..2] = x@bypW.T + bypb (global-X reads).
template<int D, int BN, bool OUTH, bool BYP>
__global__ __launch_bounds__(256) void k_gemm(const float* __restrict__ X,
                                              const float* __restrict__ W,
                                              const float* __restrict__ bias,
                                              const float* __restrict__ dinv,
                                              float* __restrict__ Y,
                                              __half* __restrict__ Yh,
                                              const float* __restrict__ bypW,
                                              const float* __restrict__ bypb,
                                              float* __restrict__ bypOut,
                                              int n_nodes) {
    __shared__ float Wt[D * 64];         // Wt[d*64+j]
    __shared__ float Xl[BN * D];         // [nl][d], no pad (reads are broadcasts)
    __shared__ float BWs[BYP ? 387 : 1];
    const int tid = threadIdx.x;
    const int n0 = blockIdx.x * BN;

    // stage W: lane j reads W[j][4dq..4dq+3] (L1-resident), writes 4 conflict-free LDS scalars
    for (int i = tid; i < 64 * (D / 4); i += 256) {
        int j = i & 63, dq = i >> 6;
        float4 w = *(const float4*)&W[j * D + 4 * dq];
        Wt[(4 * dq + 0) * 64 + j] = w.x;
        Wt[(4 * dq + 1) * 64 + j] = w.y;
        Wt[(4 * dq + 2) * 64 + j] = w.z;
        Wt[(4 * dq + 3) * 64 + j] = w.w;
    }
    // stage X: flat coalesced float4 copy
    {
        const float4* Xg = (const float4*)X;
        const int base4 = n0 * (D / 4);
        const int limit4 = n_nodes * (D / 4) - 1;
        for (int i = tid; i < BN * (D / 4); i += 256) {
            int gi = base4 + i; if (gi > limit4) gi = limit4;
            ((float4*)Xl)[i] = Xg[gi];
        }
    }
    if constexpr (BYP) {
        for (int idx = tid; idx < 387; idx += 256)
            BWs[idx] = (idx < 384) ? bypW[idx] : bypb[idx - 384];
    }
    __syncthreads();

    const int j0 = (tid & 15) * 4;
    const int nl = tid >> 4;             // 0..15
    constexpr int K = BN / 16;
    float acc[K][4];
    float b0 = 0.f, b1 = 0.f, b2 = 0.f, b3 = 0.f;
    if (bias) { b0 = bias[j0]; b1 = bias[j0 + 1]; b2 = bias[j0 + 2]; b3 = bias[j0 + 3]; }
    #pragma unroll
    for (int k = 0; k < K; k++) { acc[k][0] = b0; acc[k][1] = b1; acc[k][2] = b2; acc[k][3] = b3; }

    #pragma unroll 2
    for (int dq = 0; dq < D / 4; dq++) {
        float4 xv[K];
        #pragma unroll
        for (int k = 0; k < K; k++)
            xv[k] = *(const float4*)&Xl[(nl + 16 * k) * D + 4 * dq];  // broadcast b128
        #pragma unroll
        for (int dd = 0; dd < 4; dd++) {
            const float4 w4 = *(const float4*)&Wt[(4 * dq + dd) * 64 + j0];
            #pragma unroll
            for (int k = 0; k < K; k++) {
                float xvd = ((const float*)&xv[k])[dd];
                acc[k][0] += xvd * w4.x; acc[k][1] += xvd * w4.y;
                acc[k][2] += xvd * w4.z; acc[k][3] += xvd * w4.w;
            }
        }
    }
    #pragma unroll
    for (int k = 0; k < K; k++) {
        int n = n0 + nl + 16 * k;
        if (n < n_nodes) {
            if constexpr (OUTH) {
                float s = dinv[n];
                Half4 h;
                h.lo = __floats2half2_rn(acc[k][0] * s, acc[k][1] * s);
                h.hi = __floats2half2_rn(acc[k][2] * s, acc[k][3] * s);
                *(Half4*)&Yh[(size_t)n * 64 + j0] = h;
            } else {
                *(float4*)&Y[(size_t)n * 64 + j0] =
                    make_float4(acc[k][0], acc[k][1], acc[k][2], acc[k][3]);
            }
        }
    }
    if constexpr (BYP) {
        if (tid < 96) {
            int nl2 = tid & 31, o = tid >> 5;
            int n = n0 + nl2;
            int nc = (n < n_nodes) ? n : (n_nodes - 1);
            const float4* xr = (const float4*)&X[(size_t)nc * D];   // L1-hot rows
            float4 a4 = make_float4(0.f, 0.f, 0.f, 0.f);
            #pragma unroll 8
            for (int i = 0; i < D / 4; i++) {
                float4 v = xr[i];
                const float4 wv = *(const float4*)&BWs[o * 128 + 4 * i];  // broadcast
                a4.x += v.x * wv.x; a4.y += v.y * wv.y;
                a4.z += v.z * wv.z; a4.w += v.w * wv.w;
            }
            float b = BWs[384 + o] + a4.x + a4.y + a4.z + a4.w;
            if (n < n_nodes) bypOut[n * 3 + o] = b;
        }
    }
}

// ---------------- fused pull-aggregation ----------------
template<bool RES, bool HEAD>
__global__ __launch_bounds__(256) void k_gather(const __half* __restrict__ hBh,
                                                const float* __restrict__ dinv,
                                                const int* __restrict__ off,
                                                const int* __restrict__ csr_row,
                                                const float* __restrict__ convb,
                                                const float* __restrict__ bng,
                                                const float* __restrict__ bnb,
                                                float* __restrict__ hA,
                                                const float* __restrict__ byp,
                                                const float* __restrict__ headW,
                                                const float* __restrict__ headb,
                                                float* __restrict__ out) {
    __shared__ float HWs[HEAD ? 204 : 1];
    const int tid = threadIdx.x;
    if constexpr (HEAD) {
        for (int i = tid; i < 204; i += 256)
            HWs[i] = (i < 201) ? headW[i] : headb[i - 201];
        __syncthreads();
    }
    const int n = blockIdx.x * 4 + (tid >> 6);   // grid = NN/4 exactly
    const int lane = tid & 63;
    const int g = lane >> 3, s = lane & 7;
    const int f0 = s * 8;

    const int e0 = off[n], eEnd = off[n + 1];
    float acc[8] = {0, 0, 0, 0, 0, 0, 0, 0};
    const int nIter = (eEnd - e0 + 7) >> 3;
    for (int t = 0; t < nIter; ++t) {
        int idx = e0 + t * 8 + g;
        float w = (idx < eEnd) ? 1.0f : 0.0f;
        int idxc = (idx < eEnd) ? idx : (eEnd - 1);
        int r = csr_row[idxc];
        float4 raw = *(const float4*)(hBh + ((size_t)r << 6) + f0);
        const __half2* h2 = (const __half2*)&raw;
        #pragma unroll
        for (int q = 0; q < 4; ++q) {
            float2 f = __half22float2(h2[q]);
            acc[2 * q]     = fmaf(w, f.x, acc[2 * q]);
            acc[2 * q + 1] = fmaf(w, f.y, acc[2 * q + 1]);
        }
    }
    #pragma unroll
    for (int m = 8; m < 64; m <<= 1) {
        #pragma unroll
        for (int j = 0; j < 8; ++j)
            acc[j] += __shfl_xor(acc[j], m, 64);
    }
    {   // self-loop term
        float4 raw = *(const float4*)(hBh + ((size_t)n << 6) + f0);
        const __half2* h2 = (const __half2*)&raw;
        #pragma unroll
        for (int q = 0; q < 4; ++q) {
            float2 f = __half22float2(h2[q]);
            acc[2 * q]     += f.x;
            acc[2 * q + 1] += f.y;
        }
    }
    const float dv = dinv[n];
    const float bnscale = rsqrtf(1.0f + 1e-5f);
    float v[8];
    #pragma unroll
    for (int j = 0; j < 8; ++j) {
        float sc = bng[f0 + j] * bnscale;
        v[j] = fmaxf((acc[j] * dv + convb[f0 + j]) * sc + bnb[f0 + j], 0.0f);
    }
    if constexpr (!HEAD) {
        if (g == 0) {
            size_t o = ((size_t)n << 6) + f0;
            if constexpr (RES) {
                #pragma unroll
                for (int j = 0; j < 8; ++j) v[j] += hA[o + j];
            }
            *(float4*)&hA[o]     = make_float4(v[0], v[1], v[2], v[3]);
            *(float4*)&hA[o + 4] = make_float4(v[4], v[5], v[6], v[7]);
        }
    } else {
        float p[3];
        #pragma unroll
        for (int o = 0; o < 3; ++o) {
            float t = 0.f;
            #pragma unroll
            for (int j = 0; j < 8; ++j) t += v[j] * HWs[o * 67 + f0 + j];
            p[o] = t;
        }
        #pragma unroll
        for (int m = 1; m < 8; m <<= 1) {
            #pragma unroll
            for (int o = 0; o < 3; ++o) p[o] += __shfl_xor(p[o], m, 64);
        }
        float b0 = byp[n * 3], b1 = byp[n * 3 + 1], b2 = byp[n * 3 + 2];
        #pragma unroll
        for (int o = 0; o < 3; ++o)
            p[o] += b0 * HWs[o * 67 + 64] + b1 * HWs[o * 67 + 65] + b2 * HWs[o * 67 + 66]
                  + HWs[201 + o];
        if (lane == 0) {
            float kappa = fminf(fmaxf(p[0] * 5.0f + 2.5f, 0.2f), 10.0f);
            float tau   = fminf(fmaxf(p[2] + 0.5f, 0.05f), 2.0f);
            out[(size_t)n * 3]     = kappa;
            out[(size_t)n * 3 + 1] = p[1];
            out[(size_t)n * 3 + 2] = tau;
        }
    }
}

extern "C" void kernel_launch(void* const* d_in, const int* in_sizes, int n_in,
                              void* d_out, int out_size, void* d_ws, size_t ws_size,
                              hipStream_t stream) {
    const float* x     = (const float*)d_in[0];
    const int*   ei    = (const int*)d_in[1];
    const int*   row   = ei;
    const int*   col   = ei + NE;
    const float* projW = (const float*)d_in[2];
    const float* projb = (const float*)d_in[3];
    const float* convW[3] = { (const float*)d_in[4], (const float*)d_in[8],  (const float*)d_in[12] };
    const float* convb[3] = { (const float*)d_in[5], (const float*)d_in[9],  (const float*)d_in[13] };
    const float* bng[3]   = { (const float*)d_in[6], (const float*)d_in[10], (const float*)d_in[14] };
    const float* bnb[3]   = { (const float*)d_in[7], (const float*)d_in[11], (const float*)d_in[15] };
    const float* bypW  = (const float*)d_in[16];
    const float* bypb  = (const float*)d_in[17];
    const float* headW = (const float*)d_in[18];
    const float* headb = (const float*)d_in[19];
    float* out = (float*)d_out;

    float*  ws   = (float*)d_ws;
    float*  dinv = ws;                                  // 102400 floats
    float*  hA   = ws + 102400;                         // NN*64 fp32
    __half* hBh  = (__half*)(hA + (size_t)NN * 64);     // NN*64 fp16
    float*  byp  = (float*)(hBh + (size_t)NN * 64);     // NN*3 (+pad)
    int*    off     = (int*)(byp + 300032);             // NN+1 (pad 100096)
    int*    csr_row = off + 100096;                     // NE
    int*    bcnt    = csr_row + NE;                     // NBUK+1 (pad 784)
    int*    bcur    = bcnt + 784;                       // NBUK
    unsigned* tmp   = (unsigned*)hA;                    // aliases hA (consumed before proj)

    // bucketed CSR build (+dinv +off)
    k_zerob<<<1, 1024, 0, stream>>>(bcnt);
    k_bhist<<<256, 256, 0, stream>>>(col, bcnt);
    k_bscan<<<1, 1024, 0, stream>>>(bcnt, bcur);
    k_bucket<<<NCHUNK, 256, 0, stream>>>(row, col, bcur, tmp);
    k_build<<<NBUK, 256, 0, stream>>>(tmp, bcnt, off, dinv, csr_row);

    // proj: hA = x @ projW.T + projb  (fp32 out) + byp = x @ bypW.T + bypb
    k_gemm<128, 32, false, true><<<NN / 32, 256, 0, stream>>>(
        x, projW, projb, nullptr, hA, nullptr, bypW, bypb, byp, NN);

    for (int l = 0; l < 3; l++) {
        // hBh = (hA @ convW.T) * dinv   (fp16 out, bias deferred)
        k_gemm<64, 64, true, false><<<(NN + 63) / 64, 256, 0, stream>>>(
            hA, convW[l], nullptr, dinv, nullptr, hBh, nullptr, nullptr, nullptr, NN);
        if (l < 2)
            k_gather<true, false><<<NN / 4, 256, 0, stream>>>(
                hBh, dinv, off, csr_row, convb[l], bng[l], bnb[l], hA,
                nullptr, nullptr, nullptr, nullptr);
        else
            k_gather<false, true><<<NN / 4, 256, 0, stream>>>(
                hBh, dinv, off, csr_row, convb[l], bng[l], bnb[l], nullptr,
                byp, headW, headb, out);
    }
}

// Round 7
// 397.391 us; speedup vs baseline: 1.9021x; 1.1345x over previous
//
#include <hip/hip_runtime.h>
#include <hip/hip_fp16.h>

#define NN 100000
#define NE 1200000
#define NBUK ((NN + 127) / 128)   // 782
#define NCHUNK 128                // blocks in pass A

typedef _Float16 h8 __attribute__((ext_vector_type(8)));
typedef float f32x4 __attribute__((ext_vector_type(4)));

// ---------------- bucketed CSR build ----------------
__global__ __launch_bounds__(1024) void k_zerob(int* bcnt) {
    int i = threadIdx.x;
    if (i <= NBUK) bcnt[i] = 0;
}

__global__ __launch_bounds__(256) void k_bhist(const int* __restrict__ col, int* __restrict__ bcnt) {
    __shared__ int lh[NBUK];
    for (int i = threadIdx.x; i < NBUK; i += 256) lh[i] = 0;
    __syncthreads();
    for (int e = blockIdx.x * 256 + threadIdx.x; e < NE; e += 256 * 256)
        atomicAdd(&lh[col[e] >> 7], 1);
    __syncthreads();
    for (int i = threadIdx.x; i < NBUK; i += 256) {
        int v = lh[i];
        if (v) atomicAdd(&bcnt[i], v);
    }
}

__global__ __launch_bounds__(1024) void k_bscan(int* __restrict__ bcnt, int* __restrict__ bcur) {
    __shared__ int s[1024];
    int tid = threadIdx.x;
    int v = (tid < NBUK) ? bcnt[tid] : 0;
    s[tid] = v;
    __syncthreads();
    #pragma unroll
    for (int d = 1; d < 1024; d <<= 1) {
        int t = (tid >= d) ? s[tid - d] : 0;
        __syncthreads();
        s[tid] += t;
        __syncthreads();
    }
    if (tid < NBUK) {
        int excl = s[tid] - v;
        bcnt[tid] = excl;
        bcur[tid] = excl;
    }
    if (tid == 0) bcnt[NBUK] = NE;
}

__global__ __launch_bounds__(256) void k_bucket(const int* __restrict__ row,
                                                const int* __restrict__ col,
                                                int* __restrict__ bcur,
                                                unsigned* __restrict__ tmp) {
    __shared__ int lh[NBUK];
    const int tid = threadIdx.x;
    const int per = (NE + NCHUNK - 1) / NCHUNK;
    const int e0 = blockIdx.x * per;
    const int e1 = (e0 + per < NE) ? (e0 + per) : NE;
    for (int i = tid; i < NBUK; i += 256) lh[i] = 0;
    __syncthreads();
    for (int e = e0 + tid; e < e1; e += 256)
        atomicAdd(&lh[col[e] >> 7], 1);
    __syncthreads();
    for (int b = tid; b < NBUK; b += 256) {
        int c = lh[b];
        if (c) lh[b] = atomicAdd(&bcur[b], c);
    }
    __syncthreads();
    for (int e = e0 + tid; e < e1; e += 256) {
        int c = col[e], r = row[e];
        int pos = atomicAdd(&lh[c >> 7], 1);
        tmp[pos] = ((unsigned)r << 7) | (unsigned)(c & 127);
    }
}

__global__ __launch_bounds__(256) void k_build(const unsigned* __restrict__ tmp,
                                               const int* __restrict__ bbase,
                                               int* __restrict__ off,
                                               float* __restrict__ dinv,
                                               int* __restrict__ csr_row) {
    __shared__ int cnt[128], s[128], cur[128];
    const int b = blockIdx.x, tid = threadIdx.x;
    const int colBase = b << 7;
    const int nCols = (NN - colBase < 128) ? (NN - colBase) : 128;
    const int seg0 = bbase[b], seg1 = bbase[b + 1];
    if (tid < 128) cnt[tid] = 0;
    __syncthreads();
    for (int i = seg0 + tid; i < seg1; i += 256)
        atomicAdd(&cnt[tmp[i] & 127], 1);
    __syncthreads();
    if (tid < 128) s[tid] = cnt[tid];
    __syncthreads();
    #pragma unroll
    for (int d = 1; d < 128; d <<= 1) {
        int t = (tid < 128 && tid >= d) ? s[tid - d] : 0;
        __syncthreads();
        if (tid < 128) s[tid] += t;
        __syncthreads();
    }
    if (tid < nCols) {
        int exc = seg0 + s[tid] - cnt[tid];
        off[colBase + tid] = exc;
        cur[tid] = exc;
        dinv[colBase + tid] = rsqrtf((float)cnt[tid] + 1.0f);
    }
    if (b == 0 && tid == 0) off[NN] = NE;
    __syncthreads();
    for (int i = seg0 + tid; i < seg1; i += 256) {
        unsigned v = tmp[i];
        int pos = atomicAdd(&cur[v & 127u], 1);
        csr_row[pos] = (int)(v >> 7);
    }
}

// ---------------- MFMA fp16 GEMM: Y[n][j] = sum_d X[n][d]*W[j][d] (+b) (*dinv) ----------------
// Block = 256 thr = 4 waves, tile = 64 nodes x 64 feats. A = X (fp16 LDS), B = W (regs from LDS).
// A-frag: A[m=lane&15][k=quad*8+j]; B-frag: B[k=quad*8+j][n=lane&15]; C/D: row=quad*4+reg, col=lane&15.
template<int D, bool OUTH, bool BYP>
__global__ __launch_bounds__(256) void k_gemm(const float* __restrict__ X,
                                              const float* __restrict__ W,
                                              const float* __restrict__ bias,
                                              const float* __restrict__ dinv,
                                              float* __restrict__ Y,
                                              _Float16* __restrict__ Yh,
                                              const float* __restrict__ bypW,
                                              const float* __restrict__ bypb,
                                              float* __restrict__ bypOut,
                                              int n_nodes) {
    constexpr int RS = D + 8;            // row stride in halfs (16B-aligned rows, bank-skewed)
    constexpr int KS = D / 32;           // K-steps
    __shared__ _Float16 Xh[64 * RS];
    __shared__ _Float16 Wh[64 * RS];
    __shared__ float BWs[BYP ? 387 : 1];
    const int tid = threadIdx.x;
    const int n0 = blockIdx.x * 64;

    // stage W -> fp16 LDS (64 rows x D)
    for (int i = tid; i < 64 * (D / 8); i += 256) {
        int j = i / (D / 8), d8 = (i % (D / 8)) * 8;
        const float4* wp = (const float4*)&W[j * D + d8];
        float4 w0 = wp[0], w1 = wp[1];
        h8 h = { (_Float16)w0.x, (_Float16)w0.y, (_Float16)w0.z, (_Float16)w0.w,
                 (_Float16)w1.x, (_Float16)w1.y, (_Float16)w1.z, (_Float16)w1.w };
        *(h8*)&Wh[j * RS + d8] = h;
    }
    // stage X tile -> fp16 LDS (clamped rows)
    for (int i = tid; i < 64 * (D / 8); i += 256) {
        int nl = i / (D / 8), d8 = (i % (D / 8)) * 8;
        int n = n0 + nl; if (n >= n_nodes) n = n_nodes - 1;
        const float4* xp = (const float4*)&X[(size_t)n * D + d8];
        float4 x0 = xp[0], x1 = xp[1];
        h8 h = { (_Float16)x0.x, (_Float16)x0.y, (_Float16)x0.z, (_Float16)x0.w,
                 (_Float16)x1.x, (_Float16)x1.y, (_Float16)x1.z, (_Float16)x1.w };
        *(h8*)&Xh[nl * RS + d8] = h;
    }
    if constexpr (BYP) {
        for (int idx = tid; idx < 387; idx += 256)
            BWs[idx] = (idx < 384) ? bypW[idx] : bypb[idx - 384];
    }
    __syncthreads();

    const int wid = tid >> 6, lane = tid & 63;
    const int lm = lane & 15;            // node-in-tile (A) / feat-in-ntile (B,D)
    const int lq = lane >> 4;            // quad
    const int mBase = wid * 16;

    h8 bfrag[4][KS];
    #pragma unroll
    for (int t = 0; t < 4; ++t)
        #pragma unroll
        for (int s = 0; s < KS; ++s)
            bfrag[t][s] = *(const h8*)&Wh[(t * 16 + lm) * RS + s * 32 + lq * 8];

    f32x4 acc[4] = {};
    #pragma unroll
    for (int s = 0; s < KS; ++s) {
        h8 a = *(const h8*)&Xh[(mBase + lm) * RS + s * 32 + lq * 8];
        #pragma unroll
        for (int t = 0; t < 4; ++t)
            acc[t] = __builtin_amdgcn_mfma_f32_16x16x32_f16(a, bfrag[t][s], acc[t], 0, 0, 0);
    }

    // epilogue
    float bb[4];
    if constexpr (!OUTH) {
        #pragma unroll
        for (int t = 0; t < 4; ++t) bb[t] = bias[t * 16 + lm];
    }
    const int nodeBase = n0 + mBase + lq * 4;
    #pragma unroll
    for (int r = 0; r < 4; ++r) {
        int node = nodeBase + r;
        if (node < n_nodes) {
            if constexpr (OUTH) {
                float sdv = dinv[node];
                #pragma unroll
                for (int t = 0; t < 4; ++t)
                    Yh[(size_t)node * 64 + t * 16 + lm] = (_Float16)(acc[t][r] * sdv);
            } else {
                #pragma unroll
                for (int t = 0; t < 4; ++t)
                    Y[(size_t)node * 64 + t * 16 + lm] = acc[t][r] + bb[t];
            }
        }
    }
    if constexpr (BYP) {
        if (tid < 192) {
            int nl2 = tid & 63, o = tid >> 6;
            int n = n0 + nl2;
            int nc = (n < n_nodes) ? n : (n_nodes - 1);
            const float4* xr = (const float4*)&X[(size_t)nc * D];
            float4 a4 = make_float4(0.f, 0.f, 0.f, 0.f);
            #pragma unroll 8
            for (int i = 0; i < D / 4; i++) {
                float4 v = xr[i];
                const float4 wv = *(const float4*)&BWs[o * 128 + 4 * i];
                a4.x += v.x * wv.x; a4.y += v.y * wv.y;
                a4.z += v.z * wv.z; a4.w += v.w * wv.w;
            }
            float b = BWs[384 + o] + a4.x + a4.y + a4.z + a4.w;
            if (n < n_nodes) bypOut[n * 3 + o] = b;
        }
    }
}

// ---------------- fused pull-aggregation ----------------
template<bool RES, bool HEAD>
__global__ __launch_bounds__(256) void k_gather(const __half* __restrict__ hBh,
                                                const float* __restrict__ dinv,
                                                const int* __restrict__ off,
                                                const int* __restrict__ csr_row,
                                                const float* __restrict__ convb,
                                                const float* __restrict__ bng,
                                                const float* __restrict__ bnb,
                                                float* __restrict__ hA,
                                                const float* __restrict__ byp,
                                                const float* __restrict__ headW,
                                                const float* __restrict__ headb,
                                                float* __restrict__ out) {
    __shared__ float HWs[HEAD ? 204 : 1];
    const int tid = threadIdx.x;
    if constexpr (HEAD) {
        for (int i = tid; i < 204; i += 256)
            HWs[i] = (i < 201) ? headW[i] : headb[i - 201];
        __syncthreads();
    }
    const int n = blockIdx.x * 4 + (tid >> 6);   // grid = NN/4 exactly
    const int lane = tid & 63;
    const int g = lane >> 3, s = lane & 7;
    const int f0 = s * 8;

    const int e0 = off[n], eEnd = off[n + 1];
    float acc[8] = {0, 0, 0, 0, 0, 0, 0, 0};
    const int nIter = (eEnd - e0 + 7) >> 3;
    for (int t = 0; t < nIter; ++t) {
        int idx = e0 + t * 8 + g;
        float w = (idx < eEnd) ? 1.0f : 0.0f;
        int idxc = (idx < eEnd) ? idx : (eEnd - 1);
        int r = csr_row[idxc];
        float4 raw = *(const float4*)(hBh + ((size_t)r << 6) + f0);
        const __half2* h2 = (const __half2*)&raw;
        #pragma unroll
        for (int q = 0; q < 4; ++q) {
            float2 f = __half22float2(h2[q]);
            acc[2 * q]     = fmaf(w, f.x, acc[2 * q]);
            acc[2 * q + 1] = fmaf(w, f.y, acc[2 * q + 1]);
        }
    }
    #pragma unroll
    for (int m = 8; m < 64; m <<= 1) {
        #pragma unroll
        for (int j = 0; j < 8; ++j)
            acc[j] += __shfl_xor(acc[j], m, 64);
    }
    {   // self-loop term
        float4 raw = *(const float4*)(hBh + ((size_t)n << 6) + f0);
        const __half2* h2 = (const __half2*)&raw;
        #pragma unroll
        for (int q = 0; q < 4; ++q) {
            float2 f = __half22float2(h2[q]);
            acc[2 * q]     += f.x;
            acc[2 * q + 1] += f.y;
        }
    }
    const float dv = dinv[n];
    const float bnscale = rsqrtf(1.0f + 1e-5f);
    float v[8];
    #pragma unroll
    for (int j = 0; j < 8; ++j) {
        float sc = bng[f0 + j] * bnscale;
        v[j] = fmaxf((acc[j] * dv + convb[f0 + j]) * sc + bnb[f0 + j], 0.0f);
    }
    if constexpr (!HEAD) {
        if (g == 0) {
            size_t o = ((size_t)n << 6) + f0;
            if constexpr (RES) {
                #pragma unroll
                for (int j = 0; j < 8; ++j) v[j] += hA[o + j];
            }
            *(float4*)&hA[o]     = make_float4(v[0], v[1], v[2], v[3]);
            *(float4*)&hA[o + 4] = make_float4(v[4], v[5], v[6], v[7]);
        }
    } else {
        float p[3];
        #pragma unroll
        for (int o = 0; o < 3; ++o) {
            float t = 0.f;
            #pragma unroll
            for (int j = 0; j < 8; ++j) t += v[j] * HWs[o * 67 + f0 + j];
            p[o] = t;
        }
        #pragma unroll
        for (int m = 1; m < 8; m <<= 1) {
            #pragma unroll
            for (int o = 0; o < 3; ++o) p[o] += __shfl_xor(p[o], m, 64);
        }
        float b0 = byp[n * 3], b1 = byp[n * 3 + 1], b2 = byp[n * 3 + 2];
        #pragma unroll
        for (int o = 0; o < 3; ++o)
            p[o] += b0 * HWs[o * 67 + 64] + b1 * HWs[o * 67 + 65] + b2 * HWs[o * 67 + 66]
                  + HWs[201 + o];
        if (lane == 0) {
            float kappa = fminf(fmaxf(p[0] * 5.0f + 2.5f, 0.2f), 10.0f);
            float tau   = fminf(fmaxf(p[2] + 0.5f, 0.05f), 2.0f);
            out[(size_t)n * 3]     = kappa;
            out[(size_t)n * 3 + 1] = p[1];
            out[(size_t)n * 3 + 2] = tau;
        }
    }
}

extern "C" void kernel_launch(void* const* d_in, const int* in_sizes, int n_in,
                              void* d_out, int out_size, void* d_ws, size_t ws_size,
                              hipStream_t stream) {
    const float* x     = (const float*)d_in[0];
    const int*   ei    = (const int*)d_in[1];
    const int*   row   = ei;
    const int*   col   = ei + NE;
    const float* projW = (const float*)d_in[2];
    const float* projb = (const float*)d_in[3];
    const float* convW[3] = { (const float*)d_in[4], (const float*)d_in[8],  (const float*)d_in[12] };
    const float* convb[3] = { (const float*)d_in[5], (const float*)d_in[9],  (const float*)d_in[13] };
    const float* bng[3]   = { (const float*)d_in[6], (const float*)d_in[10], (const float*)d_in[14] };
    const float* bnb[3]   = { (const float*)d_in[7], (const float*)d_in[11], (const float*)d_in[15] };
    const float* bypW  = (const float*)d_in[16];
    const float* bypb  = (const float*)d_in[17];
    const float* headW = (const float*)d_in[18];
    const float* headb = (const float*)d_in[19];
    float* out = (float*)d_out;

    float*    ws   = (float*)d_ws;
    float*    dinv = ws;                                  // 102400 floats
    float*    hA   = ws + 102400;                         // NN*64 fp32
    _Float16* hBh  = (_Float16*)(hA + (size_t)NN * 64);   // NN*64 fp16
    float*    byp  = (float*)(hBh + (size_t)NN * 64);     // NN*3 (+pad)
    int*      off     = (int*)(byp + 300032);             // NN+1 (pad 100096)
    int*      csr_row = off + 100096;                     // NE
    int*      bcnt    = csr_row + NE;                     // NBUK+1 (pad 784)
    int*      bcur    = bcnt + 784;                       // NBUK
    unsigned* tmp     = (unsigned*)hA;                    // aliases hA (consumed before proj)

    // bucketed CSR build (+dinv +off)
    k_zerob<<<1, 1024, 0, stream>>>(bcnt);
    k_bhist<<<256, 256, 0, stream>>>(col, bcnt);
    k_bscan<<<1, 1024, 0, stream>>>(bcnt, bcur);
    k_bucket<<<NCHUNK, 256, 0, stream>>>(row, col, bcur, tmp);
    k_build<<<NBUK, 256, 0, stream>>>(tmp, bcnt, off, dinv, csr_row);

    // proj: hA = x @ projW.T + projb  (fp32 out) + byp = x @ bypW.T + bypb
    k_gemm<128, false, true><<<(NN + 63) / 64, 256, 0, stream>>>(
        x, projW, projb, nullptr, hA, nullptr, bypW, bypb, byp, NN);

    for (int l = 0; l < 3; l++) {
        // hBh = (hA @ convW.T) * dinv   (fp16 out, bias deferred)
        k_gemm<64, true, false><<<(NN + 63) / 64, 256, 0, stream>>>(
            hA, convW[l], nullptr, dinv, nullptr, hBh, nullptr, nullptr, nullptr, NN);
        if (l < 2)
            k_gather<true, false><<<NN / 4, 256, 0, stream>>>(
                (const __half*)hBh, dinv, off, csr_row, convb[l], bng[l], bnb[l], hA,
                nullptr, nullptr, nullptr, nullptr);
        else
            k_gather<false, true><<<NN / 4, 256, 0, stream>>>(
                (const __half*)hBh, dinv, off, csr_row, convb[l], bng[l], bnb[l], nullptr,
                byp, headW, headb, out);
    }
}

// Round 8
// 385.247 us; speedup vs baseline: 1.9621x; 1.0315x over previous
//
#include <hip/hip_runtime.h>
#include <hip/hip_fp16.h>

#define NN 100000
#define NE 1200000
#define NBUK ((NN + 127) / 128)   // 782
#define NCHUNK 128                // blocks in pass A

typedef _Float16 h8 __attribute__((ext_vector_type(8)));
typedef float f32x4 __attribute__((ext_vector_type(4)));

// ---------------- bucketed CSR build ----------------
__global__ __launch_bounds__(1024) void k_zerob(int* bcnt) {
    int i = threadIdx.x;
    if (i <= NBUK) bcnt[i] = 0;
}

__global__ __launch_bounds__(256) void k_bhist(const int* __restrict__ col, int* __restrict__ bcnt) {
    __shared__ int lh[NBUK];
    for (int i = threadIdx.x; i < NBUK; i += 256) lh[i] = 0;
    __syncthreads();
    for (int e = blockIdx.x * 256 + threadIdx.x; e < NE; e += 256 * 256)
        atomicAdd(&lh[col[e] >> 7], 1);
    __syncthreads();
    for (int i = threadIdx.x; i < NBUK; i += 256) {
        int v = lh[i];
        if (v) atomicAdd(&bcnt[i], v);
    }
}

__global__ __launch_bounds__(1024) void k_bscan(int* __restrict__ bcnt, int* __restrict__ bcur) {
    __shared__ int s[1024];
    int tid = threadIdx.x;
    int v = (tid < NBUK) ? bcnt[tid] : 0;
    s[tid] = v;
    __syncthreads();
    #pragma unroll
    for (int d = 1; d < 1024; d <<= 1) {
        int t = (tid >= d) ? s[tid - d] : 0;
        __syncthreads();
        s[tid] += t;
        __syncthreads();
    }
    if (tid < NBUK) {
        int excl = s[tid] - v;
        bcnt[tid] = excl;
        bcur[tid] = excl;
    }
    if (tid == 0) bcnt[NBUK] = NE;
}

__global__ __launch_bounds__(256) void k_bucket(const int* __restrict__ row,
                                                const int* __restrict__ col,
                                                int* __restrict__ bcur,
                                                unsigned* __restrict__ tmp) {
    __shared__ int lh[NBUK];
    const int tid = threadIdx.x;
    const int per = (NE + NCHUNK - 1) / NCHUNK;
    const int e0 = blockIdx.x * per;
    const int e1 = (e0 + per < NE) ? (e0 + per) : NE;
    for (int i = tid; i < NBUK; i += 256) lh[i] = 0;
    __syncthreads();
    for (int e = e0 + tid; e < e1; e += 256)
        atomicAdd(&lh[col[e] >> 7], 1);
    __syncthreads();
    for (int b = tid; b < NBUK; b += 256) {
        int c = lh[b];
        if (c) lh[b] = atomicAdd(&bcur[b], c);
    }
    __syncthreads();
    for (int e = e0 + tid; e < e1; e += 256) {
        int c = col[e], r = row[e];
        int pos = atomicAdd(&lh[c >> 7], 1);
        tmp[pos] = ((unsigned)r << 7) | (unsigned)(c & 127);
    }
}

__global__ __launch_bounds__(256) void k_build(const unsigned* __restrict__ tmp,
                                               const int* __restrict__ bbase,
                                               int* __restrict__ off,
                                               float* __restrict__ dinv,
                                               int* __restrict__ csr_row) {
    __shared__ int cnt[128], s[128], cur[128];
    const int b = blockIdx.x, tid = threadIdx.x;
    const int colBase = b << 7;
    const int nCols = (NN - colBase < 128) ? (NN - colBase) : 128;
    const int seg0 = bbase[b], seg1 = bbase[b + 1];
    if (tid < 128) cnt[tid] = 0;
    __syncthreads();
    for (int i = seg0 + tid; i < seg1; i += 256)
        atomicAdd(&cnt[tmp[i] & 127], 1);
    __syncthreads();
    if (tid < 128) s[tid] = cnt[tid];
    __syncthreads();
    #pragma unroll
    for (int d = 1; d < 128; d <<= 1) {
        int t = (tid < 128 && tid >= d) ? s[tid - d] : 0;
        __syncthreads();
        if (tid < 128) s[tid] += t;
        __syncthreads();
    }
    if (tid < nCols) {
        int exc = seg0 + s[tid] - cnt[tid];
        off[colBase + tid] = exc;
        cur[tid] = exc;
        dinv[colBase + tid] = rsqrtf((float)cnt[tid] + 1.0f);
    }
    if (b == 0 && tid == 0) off[NN] = NE;
    __syncthreads();
    for (int i = seg0 + tid; i < seg1; i += 256) {
        unsigned v = tmp[i];
        int pos = atomicAdd(&cur[v & 127u], 1);
        csr_row[pos] = (int)(v >> 7);
    }
}

// ---------------- MFMA fp16 GEMM ----------------
template<int D, bool OUTH, bool BYP>
__global__ __launch_bounds__(256) void k_gemm(const float* __restrict__ X,
                                              const float* __restrict__ W,
                                              const float* __restrict__ bias,
                                              const float* __restrict__ dinv,
                                              float* __restrict__ Y,
                                              _Float16* __restrict__ Yh,
                                              const float* __restrict__ bypW,
                                              const float* __restrict__ bypb,
                                              float* __restrict__ bypOut,
                                              int n_nodes) {
    constexpr int RS = D + 8;
    constexpr int KS = D / 32;
    __shared__ _Float16 Xh[64 * RS];
    __shared__ _Float16 Wh[64 * RS];
    __shared__ float BWs[BYP ? 387 : 1];
    const int tid = threadIdx.x;
    const int n0 = blockIdx.x * 64;

    for (int i = tid; i < 64 * (D / 8); i += 256) {
        int j = i / (D / 8), d8 = (i % (D / 8)) * 8;
        const float4* wp = (const float4*)&W[j * D + d8];
        float4 w0 = wp[0], w1 = wp[1];
        h8 h = { (_Float16)w0.x, (_Float16)w0.y, (_Float16)w0.z, (_Float16)w0.w,
                 (_Float16)w1.x, (_Float16)w1.y, (_Float16)w1.z, (_Float16)w1.w };
        *(h8*)&Wh[j * RS + d8] = h;
    }
    for (int i = tid; i < 64 * (D / 8); i += 256) {
        int nl = i / (D / 8), d8 = (i % (D / 8)) * 8;
        int n = n0 + nl; if (n >= n_nodes) n = n_nodes - 1;
        const float4* xp = (const float4*)&X[(size_t)n * D + d8];
        float4 x0 = xp[0], x1 = xp[1];
        h8 h = { (_Float16)x0.x, (_Float16)x0.y, (_Float16)x0.z, (_Float16)x0.w,
                 (_Float16)x1.x, (_Float16)x1.y, (_Float16)x1.z, (_Float16)x1.w };
        *(h8*)&Xh[nl * RS + d8] = h;
    }
    if constexpr (BYP) {
        for (int idx = tid; idx < 387; idx += 256)
            BWs[idx] = (idx < 384) ? bypW[idx] : bypb[idx - 384];
    }
    __syncthreads();

    const int wid = tid >> 6, lane = tid & 63;
    const int lm = lane & 15;
    const int lq = lane >> 4;
    const int mBase = wid * 16;

    h8 bfrag[4][KS];
    #pragma unroll
    for (int t = 0; t < 4; ++t)
        #pragma unroll
        for (int s = 0; s < KS; ++s)
            bfrag[t][s] = *(const h8*)&Wh[(t * 16 + lm) * RS + s * 32 + lq * 8];

    f32x4 acc[4] = {};
    #pragma unroll
    for (int s = 0; s < KS; ++s) {
        h8 a = *(const h8*)&Xh[(mBase + lm) * RS + s * 32 + lq * 8];
        #pragma unroll
        for (int t = 0; t < 4; ++t)
            acc[t] = __builtin_amdgcn_mfma_f32_16x16x32_f16(a, bfrag[t][s], acc[t], 0, 0, 0);
    }

    float bb[4];
    if constexpr (!OUTH) {
        #pragma unroll
        for (int t = 0; t < 4; ++t) bb[t] = bias[t * 16 + lm];
    }
    const int nodeBase = n0 + mBase + lq * 4;
    #pragma unroll
    for (int r = 0; r < 4; ++r) {
        int node = nodeBase + r;
        if (node < n_nodes) {
            if constexpr (OUTH) {
                float sdv = dinv[node];
                #pragma unroll
                for (int t = 0; t < 4; ++t)
                    Yh[(size_t)node * 64 + t * 16 + lm] = (_Float16)(acc[t][r] * sdv);
            } else {
                #pragma unroll
                for (int t = 0; t < 4; ++t)
                    Y[(size_t)node * 64 + t * 16 + lm] = acc[t][r] + bb[t];
            }
        }
    }
    if constexpr (BYP) {
        if (tid < 192) {
            int nl2 = tid & 63, o = tid >> 6;
            int n = n0 + nl2;
            int nc = (n < n_nodes) ? n : (n_nodes - 1);
            const float4* xr = (const float4*)&X[(size_t)nc * D];
            float4 a4 = make_float4(0.f, 0.f, 0.f, 0.f);
            #pragma unroll 8
            for (int i = 0; i < D / 4; i++) {
                float4 v = xr[i];
                const float4 wv = *(const float4*)&BWs[o * 128 + 4 * i];
                a4.x += v.x * wv.x; a4.y += v.y * wv.y;
                a4.z += v.z * wv.z; a4.w += v.w * wv.w;
            }
            float b = BWs[384 + o] + a4.x + a4.y + a4.z + a4.w;
            if (n < n_nodes) bypOut[n * 3 + o] = b;
        }
    }
}

// ---------------- fused pull-aggregation (packed fp16 accumulation) ----------------
template<bool RES, bool HEAD>
__global__ __launch_bounds__(256) void k_gather(const _Float16* __restrict__ hBh,
                                                const float* __restrict__ dinv,
                                                const int* __restrict__ off,
                                                const int* __restrict__ csr_row,
                                                const float* __restrict__ convb,
                                                const float* __restrict__ bng,
                                                const float* __restrict__ bnb,
                                                float* __restrict__ hA,
                                                const float* __restrict__ byp,
                                                const float* __restrict__ headW,
                                                const float* __restrict__ headb,
                                                float* __restrict__ out) {
    __shared__ float HWs[HEAD ? 204 : 1];
    const int tid = threadIdx.x;
    if constexpr (HEAD) {
        for (int i = tid; i < 204; i += 256)
            HWs[i] = (i < 201) ? headW[i] : headb[i - 201];
        __syncthreads();
    }
    const int n = blockIdx.x * 4 + (tid >> 6);   // grid = NN/4 exactly
    const int lane = tid & 63;
    const int g = lane >> 3, s = lane & 7;
    const int f0 = s * 8;

    const int e0 = off[n], eEnd = off[n + 1];
    h8 acch = (h8)(_Float16)0;
    const int nIter = (eEnd - e0 + 7) >> 3;
    for (int t = 0; t < nIter; ++t) {
        int idx = e0 + t * 8 + g;
        bool valid = idx < eEnd;
        int idxc = valid ? idx : e0;
        int r = csr_row[idxc];
        h8 raw = *(const h8*)(hBh + ((size_t)r << 6) + f0);
        _Float16 w = valid ? (_Float16)1.0f : (_Float16)0.0f;
        h8 wv = { w, w, w, w, w, w, w, w };
        acch = raw * wv + acch;            // v_pk_fma_f16 x4
    }
    // butterfly over edge-groups: packed adds, 4 int shuffles per level
    #pragma unroll
    for (int m = 8; m < 64; m <<= 1) {
        int4 ai = *(int4*)&acch;
        int4 bi;
        bi.x = __shfl_xor(ai.x, m, 64);
        bi.y = __shfl_xor(ai.y, m, 64);
        bi.z = __shfl_xor(ai.z, m, 64);
        bi.w = __shfl_xor(ai.w, m, 64);
        acch = acch + *(h8*)&bi;
    }
    // self-loop term
    acch = acch + *(const h8*)(hBh + ((size_t)n << 6) + f0);

    float acc[8];
    #pragma unroll
    for (int j = 0; j < 8; ++j) acc[j] = (float)acch[j];

    const float dv = dinv[n];
    const float bnscale = rsqrtf(1.0f + 1e-5f);
    float v[8];
    #pragma unroll
    for (int j = 0; j < 8; ++j) {
        float sc = bng[f0 + j] * bnscale;
        v[j] = fmaxf((acc[j] * dv + convb[f0 + j]) * sc + bnb[f0 + j], 0.0f);
    }
    if constexpr (!HEAD) {
        if (g == 0) {
            size_t o = ((size_t)n << 6) + f0;
            if constexpr (RES) {
                #pragma unroll
                for (int j = 0; j < 8; ++j) v[j] += hA[o + j];
            }
            *(float4*)&hA[o]     = make_float4(v[0], v[1], v[2], v[3]);
            *(float4*)&hA[o + 4] = make_float4(v[4], v[5], v[6], v[7]);
        }
    } else {
        float p[3];
        #pragma unroll
        for (int o = 0; o < 3; ++o) {
            float t = 0.f;
            #pragma unroll
            for (int j = 0; j < 8; ++j) t += v[j] * HWs[o * 67 + f0 + j];
            p[o] = t;
        }
        #pragma unroll
        for (int m = 1; m < 8; m <<= 1) {
            #pragma unroll
            for (int o = 0; o < 3; ++o) p[o] += __shfl_xor(p[o], m, 64);
        }
        float b0 = byp[n * 3], b1 = byp[n * 3 + 1], b2 = byp[n * 3 + 2];
        #pragma unroll
        for (int o = 0; o < 3; ++o)
            p[o] += b0 * HWs[o * 67 + 64] + b1 * HWs[o * 67 + 65] + b2 * HWs[o * 67 + 66]
                  + HWs[201 + o];
        if (lane == 0) {
            float kappa = fminf(fmaxf(p[0] * 5.0f + 2.5f, 0.2f), 10.0f);
            float tau   = fminf(fmaxf(p[2] + 0.5f, 0.05f), 2.0f);
            out[(size_t)n * 3]     = kappa;
            out[(size_t)n * 3 + 1] = p[1];
            out[(size_t)n * 3 + 2] = tau;
        }
    }
}

extern "C" void kernel_launch(void* const* d_in, const int* in_sizes, int n_in,
                              void* d_out, int out_size, void* d_ws, size_t ws_size,
                              hipStream_t stream) {
    const float* x     = (const float*)d_in[0];
    const int*   ei    = (const int*)d_in[1];
    const int*   row   = ei;
    const int*   col   = ei + NE;
    const float* projW = (const float*)d_in[2];
    const float* projb = (const float*)d_in[3];
    const float* convW[3] = { (const float*)d_in[4], (const float*)d_in[8],  (const float*)d_in[12] };
    const float* convb[3] = { (const float*)d_in[5], (const float*)d_in[9],  (const float*)d_in[13] };
    const float* bng[3]   = { (const float*)d_in[6], (const float*)d_in[10], (const float*)d_in[14] };
    const float* bnb[3]   = { (const float*)d_in[7], (const float*)d_in[11], (const float*)d_in[15] };
    const float* bypW  = (const float*)d_in[16];
    const float* bypb  = (const float*)d_in[17];
    const float* headW = (const float*)d_in[18];
    const float* headb = (const float*)d_in[19];
    float* out = (float*)d_out;

    float*    ws   = (float*)d_ws;
    float*    dinv = ws;                                  // 102400 floats
    float*    hA   = ws + 102400;                         // NN*64 fp32
    _Float16* hBh  = (_Float16*)(hA + (size_t)NN * 64);   // NN*64 fp16
    float*    byp  = (float*)(hBh + (size_t)NN * 64);     // NN*3 (+pad)
    int*      off     = (int*)(byp + 300032);             // NN+1 (pad 100096)
    int*      csr_row = off + 100096;                     // NE
    int*      bcnt    = csr_row + NE;                     // NBUK+1 (pad 784)
    int*      bcur    = bcnt + 784;                       // NBUK
    unsigned* tmp     = (unsigned*)hA;                    // aliases hA (consumed before proj)

    // bucketed CSR build (+dinv +off)
    k_zerob<<<1, 1024, 0, stream>>>(bcnt);
    k_bhist<<<256, 256, 0, stream>>>(col, bcnt);
    k_bscan<<<1, 1024, 0, stream>>>(bcnt, bcur);
    k_bucket<<<NCHUNK, 256, 0, stream>>>(row, col, bcur, tmp);
    k_build<<<NBUK, 256, 0, stream>>>(tmp, bcnt, off, dinv, csr_row);

    // proj: hA = x @ projW.T + projb  (fp32 out) + byp = x @ bypW.T + bypb
    k_gemm<128, false, true><<<(NN + 63) / 64, 256, 0, stream>>>(
        x, projW, projb, nullptr, hA, nullptr, bypW, bypb, byp, NN);

    for (int l = 0; l < 3; l++) {
        // hBh = (hA @ convW.T) * dinv   (fp16 out, bias deferred)
        k_gemm<64, true, false><<<(NN + 63) / 64, 256, 0, stream>>>(
            hA, convW[l], nullptr, dinv, nullptr, hBh, nullptr, nullptr, nullptr, NN);
        if (l < 2)
            k_gather<true, false><<<NN / 4, 256, 0, stream>>>(
                hBh, dinv, off, csr_row, convb[l], bng[l], bnb[l], hA,
                nullptr, nullptr, nullptr, nullptr);
        else
            k_gather<false, true><<<NN / 4, 256, 0, stream>>>(
                hBh, dinv, off, csr_row, convb[l], bng[l], bnb[l], nullptr,
                byp, headW, headb, out);
    }
}